// Round 8
// baseline (133.451 us; speedup 1.0000x reference)
//
#include <hip/hip_runtime.h>
#include <math.h>

// Time-chunked + warm-up parallelization of a fading-memory recurrence
// pipeline: pre-biquad x2 -> gain/bias -> GRU(H=1) -> post-biquad x2.
// Each thread = (batch, chunk), starting WARMUP steps early with zero states.
// CHUNK=16/WARMUP=16: 32 serial steps/thread, 262144 threads = 4 waves/SIMD.
//
// MEASUREMENT ROUND: main kernel launched 3x (idempotent, identical output).
// main_dur = (dur_r8 - dur_r6) / 2 -- harness overhead cancels exactly.

#ifndef CHUNK
#define CHUNK 16
#endif
#ifndef WARMUP
#define WARMUP 16
#endif
#define NWQ ((WARMUP + CHUNK) / 4)   // quads per full window (8)
#define NCQ (CHUNK / 4)              // quads per chunk (4)

__device__ __forceinline__ float fast_rcp(float x) {
    return __builtin_amdgcn_rcpf(x);
}
__device__ __forceinline__ float fast_exp2(float x) {
    return __builtin_amdgcn_exp2f(x);
}
__device__ __forceinline__ float sigm_fast(float v) {
    return fast_rcp(1.0f + fast_exp2(-1.44269504088896341f * v));
}
__device__ __forceinline__ float tanh_fast(float v) {
    return fmaf(-2.0f, fast_rcp(1.0f + fast_exp2(2.88539008177792681f * v)), 1.0f);
}

// ---- kernel 1: per-batch knob MLP -> folded GRU input constants ----------
__global__ __launch_bounds__(64) void knob_precompute(
    const float* __restrict__ knobs,
    const float* __restrict__ gw_ih, const float* __restrict__ gb_ih,
    const float* __restrict__ gb_hh,
    const float* __restrict__ kw1, const float* __restrict__ kb1,
    const float* __restrict__ kw2, const float* __restrict__ kb2,
    float* __restrict__ ws, int B)
{
    const int b = threadIdx.x;
    if (b >= B) return;
    const float knob = knobs[b];
    float a0 = kb2[0], a1 = kb2[1];
#pragma unroll
    for (int j = 0; j < 16; ++j) {
        const float hj = tanh_fast(fmaf(knob, kw1[j], kb1[j]));
        a0 = fmaf(hj, kw2[j], a0);
        a1 = fmaf(hj, kw2[16 + j], a1);
    }
    const float p0 = sigm_fast(a0);
    const float p1 = sigm_fast(a1);
    const float gain = fast_exp2(1.44269504088896341f * fmaf(p0, 4.0f, -2.0f));
    const float bias = 0.1f * p1;

    const float LOG2E = 1.44269504088896341f;
    const float TWOLOG2E = 2.88539008177792681f;
    const float kr_u = -LOG2E * gw_ih[0];
    const float kr_c = -LOG2E * (gb_ih[0] + gb_hh[0]);
    const float kz_u = -LOG2E * gw_ih[1];
    const float kz_c = -LOG2E * (gb_ih[1] + gb_hh[1]);
    const float kn_u = TWOLOG2E * gw_ih[2];
    const float kn_ci = TWOLOG2E * gb_ih[2];

    float* w = ws + b * 6;
    w[0] = kr_u * gain; w[1] = fmaf(kr_u, bias, kr_c);
    w[2] = kz_u * gain; w[3] = fmaf(kz_u, bias, kz_c);
    w[4] = kn_u * gain; w[5] = fmaf(kn_u, bias, kn_ci);
}

// ---- kernel 2: fused recurrence ------------------------------------------
__global__ __launch_bounds__(256) void preamp_fused(
    const float* __restrict__ x,
    const float* __restrict__ pre_c, const float* __restrict__ post_c,
    const float* __restrict__ gw_hh, const float* __restrict__ gb_hh,
    const float* __restrict__ gw_out, const float* __restrict__ gb_out,
    const float* __restrict__ ws,
    float* __restrict__ out, int L, int cshift)
{
    const int tid = blockIdx.x * 256 + threadIdx.x;
    const int b = tid >> cshift;               // batch (nchunks = 1<<cshift)
    const int c = tid & ((1 << cshift) - 1);   // chunk within batch

    // ---- per-batch folded GRU input constants ----
    const float* w = ws + b * 6;
    const float Kry = w[0], Krc = w[1];
    const float Kzy = w[2], Kzc = w[3];
    const float Kny = w[4], Knc = w[5];

    // ---- filter coefficients (uniform -> scalar) ----
    const float f0b0 = pre_c[0],  f0b1 = pre_c[1],  f0b2 = pre_c[2];
    const float f0a1 = -pre_c[3], f0a2 = -pre_c[4];
    const float f1b0 = pre_c[5],  f1b1 = pre_c[6],  f1b2 = pre_c[7];
    const float f1a1 = -pre_c[8], f1a2 = -pre_c[9];
    const float f2b0 = post_c[0], f2b1 = post_c[1], f2b2 = post_c[2];
    const float f2a1 = -post_c[3], f2a2 = -post_c[4];
    const float f3b0 = post_c[5], f3b1 = post_c[6], f3b2 = post_c[7];
    const float f3a1 = -post_c[8], f3a2 = -post_c[9];

    // ---- h-side GRU constants (batch-independent) ----
    const float LOG2E = 1.44269504088896341f;
    const float TWOLOG2E = 2.88539008177792681f;
    const float kr_h = -LOG2E * gw_hh[0];
    const float kz_h = -LOG2E * gw_hh[1];
    const float kn_h = TWOLOG2E * gw_hh[2];
    const float kn_c = TWOLOG2E * gb_hh[2];
    const float wo = gw_out[0], bo = gb_out[0];

    // ---- states (zero at window start; exact when start==0) ----
    float ax1 = 0.f, ax2 = 0.f, ay1 = 0.f, ay2 = 0.f;   // pre 0
    float bx1 = 0.f, bx2 = 0.f, by1 = 0.f, by2 = 0.f;   // pre 1
    float h = 0.f;                                       // GRU
    float cx1 = 0.f, cx2 = 0.f, cy1 = 0.f, cy2 = 0.f;   // post 0
    float dx1 = 0.f, dx2 = 0.f, dy1 = 0.f, dy2 = 0.f;   // post 1

    const long base = (long)b * (long)L;
    const float* xp = x + base;
    float* op = out + base;
    const int t0 = c * CHUNK;

#define STEP(xt, dst)                                                        \
    {                                                                        \
        float ff = fmaf(f0b1, ax1, f0b0 * (xt));                             \
        ff = fmaf(f0b2, ax2, ff);                                            \
        ff = fmaf(f0a2, ay2, ff);                                            \
        const float y = fmaf(f0a1, ay1, ff);                                 \
        ax2 = ax1; ax1 = (xt); ay2 = ay1; ay1 = y;                           \
        float ff1 = fmaf(f1b1, bx1, f1b0 * y);                               \
        ff1 = fmaf(f1b2, bx2, ff1);                                          \
        ff1 = fmaf(f1a2, by2, ff1);                                          \
        const float y2 = fmaf(f1a1, by1, ff1);                               \
        bx2 = bx1; bx1 = y; by2 = by1; by1 = y2;                             \
        const float ur = fmaf(Kry, y2, Krc);                                 \
        const float uz = fmaf(Kzy, y2, Kzc);                                 \
        const float un = fmaf(Kny, y2, Knc);                                 \
        const float hn = fmaf(kn_h, h, kn_c);                                \
        const float r = fast_rcp(1.0f + fast_exp2(fmaf(kr_h, h, ur)));       \
        const float z = fast_rcp(1.0f + fast_exp2(fmaf(kz_h, h, uz)));       \
        const float n = fmaf(-2.0f,                                          \
            fast_rcp(1.0f + fast_exp2(fmaf(r, hn, un))), 1.0f);              \
        h = fmaf(z, h - n, n);                                               \
        const float v = fmaf(wo, h, bo);                                     \
        float ff2 = fmaf(f2b1, cx1, f2b0 * v);                               \
        ff2 = fmaf(f2b2, cx2, ff2);                                          \
        ff2 = fmaf(f2a2, cy2, ff2);                                          \
        const float q = fmaf(f2a1, cy1, ff2);                                \
        cx2 = cx1; cx1 = v; cy2 = cy1; cy1 = q;                              \
        float ff3 = fmaf(f3b1, dx1, f3b0 * q);                               \
        ff3 = fmaf(f3b2, dx2, ff3);                                          \
        ff3 = fmaf(f3a2, dy2, ff3);                                          \
        const float q2 = fmaf(f3a1, dy1, ff3);                               \
        dx2 = dx1; dx1 = q; dy2 = dy1; dy1 = q2;                             \
        dst = q2;                                                            \
    }

    float sink;
    if (c != 0) {
        // ---- full window: issue ALL 8 loads up front, one latency --------
        const float* wb = xp + (t0 - WARMUP);
        float4 qb[NWQ];
#pragma unroll
        for (int i = 0; i < NWQ; ++i)
            qb[i] = *reinterpret_cast<const float4*>(wb + 4 * i);
        // warm-up (discarded)
#pragma unroll
        for (int i = 0; i < WARMUP / 4; ++i) {
            STEP(qb[i].x, sink); STEP(qb[i].y, sink);
            STEP(qb[i].z, sink); STEP(qb[i].w, sink);
        }
        // chunk (stored)
#pragma unroll
        for (int i = 0; i < NCQ; ++i) {
            float4 o;
            const int j = WARMUP / 4 + i;
            STEP(qb[j].x, o.x); STEP(qb[j].y, o.y);
            STEP(qb[j].z, o.z); STEP(qb[j].w, o.w);
            *reinterpret_cast<float4*>(op + t0 + 4 * i) = o;
        }
    } else {
        // ---- c == 0: zero states at t=0 are EXACT; no warm-up ------------
        float4 qb[NCQ];
#pragma unroll
        for (int i = 0; i < NCQ; ++i)
            qb[i] = *reinterpret_cast<const float4*>(xp + 4 * i);
#pragma unroll
        for (int i = 0; i < NCQ; ++i) {
            float4 o;
            STEP(qb[i].x, o.x); STEP(qb[i].y, o.y);
            STEP(qb[i].z, o.z); STEP(qb[i].w, o.w);
            *reinterpret_cast<float4*>(op + 4 * i) = o;
        }
    }
#undef STEP
    (void)sink;
}

extern "C" void kernel_launch(void* const* d_in, const int* in_sizes, int n_in,
                              void* d_out, int out_size, void* d_ws, size_t ws_size,
                              hipStream_t stream) {
    const float* x      = (const float*)d_in[0];
    const float* knobs  = (const float*)d_in[1];
    const float* pre_c  = (const float*)d_in[2];
    const float* post_c = (const float*)d_in[3];
    const float* gw_ih  = (const float*)d_in[4];
    const float* gw_hh  = (const float*)d_in[5];
    const float* gb_ih  = (const float*)d_in[6];
    const float* gb_hh  = (const float*)d_in[7];
    const float* gw_out = (const float*)d_in[8];
    const float* gb_out = (const float*)d_in[9];
    const float* kw1    = (const float*)d_in[10];
    const float* kb1    = (const float*)d_in[11];
    const float* kw2    = (const float*)d_in[12];
    const float* kb2    = (const float*)d_in[13];
    float* out = (float*)d_out;
    float* ws  = (float*)d_ws;

    const int B = in_sizes[1];                 // 64
    const int L = in_sizes[0] / B;             // 65536
    const int nchunks = L / CHUNK;             // 4096 (power of two)
    int cshift = 0; while ((1 << cshift) < nchunks) ++cshift;
    const int threads = B * nchunks;           // 262144

    knob_precompute<<<dim3(1), dim3(64), 0, stream>>>(
        knobs, gw_ih, gb_ih, gb_hh, kw1, kb1, kw2, kb2, ws, B);
    // MEASUREMENT: 3 identical (idempotent) launches; (dur_r8-dur_r6)/2 = main.
    for (int rep = 0; rep < 3; ++rep) {
        preamp_fused<<<dim3(threads / 256), dim3(256), 0, stream>>>(
            x, pre_c, post_c, gw_hh, gb_hh, gw_out, gb_out, ws, out, L, cshift);
    }
}

// Round 9
// 104.497 us; speedup vs baseline: 1.2771x; 1.2771x over previous
//
#include <hip/hip_runtime.h>
#include <math.h>

// Time-chunked + warm-up parallelization of a fading-memory recurrence
// pipeline: pre-biquad x2 -> gain/bias -> GRU(H=1) -> post-biquad x2.
// Each thread = (batch, chunk), starting WARMUP steps early with zero states.
// CHUNK=16/WARMUP=16: 32 serial steps/thread, 262144 threads = 4 waves/SIMD.
//
// This round: PHASE-SPLIT scheduling. A/B measurement (r8) pinned the main
// kernel at 12.8us vs a ~6.3us issue floor -- the gap is per-step dependent-
// chain stall (pre->GRU->post serialized ~120cy/step). Phases run each stage
// over the whole 32-sample register window: biquad phases have 2-fma loop
// carry (~8cy) with huge cross-step ILP; only the GRU phase keeps the ~44cy
// serial core. Window buffer reused in place (x -> y2 -> v -> q2): VGPR ~90.
// Per-time-step math is IDENTICAL -> absmax must stay bit-equal (0.00390625).

#ifndef CHUNK
#define CHUNK 16
#endif
#ifndef WARMUP
#define WARMUP 16
#endif
#define NWQ ((WARMUP + CHUNK) / 4)   // quads per full window (8)
#define NCQ (CHUNK / 4)              // quads per chunk (4)

__device__ __forceinline__ float fast_rcp(float x) {
    return __builtin_amdgcn_rcpf(x);
}
__device__ __forceinline__ float fast_exp2(float x) {
    return __builtin_amdgcn_exp2f(x);
}
__device__ __forceinline__ float sigm_fast(float v) {
    return fast_rcp(1.0f + fast_exp2(-1.44269504088896341f * v));
}
__device__ __forceinline__ float tanh_fast(float v) {
    return fmaf(-2.0f, fast_rcp(1.0f + fast_exp2(2.88539008177792681f * v)), 1.0f);
}

// ---- kernel 1: per-batch knob MLP -> folded GRU input constants ----------
__global__ __launch_bounds__(64) void knob_precompute(
    const float* __restrict__ knobs,
    const float* __restrict__ gw_ih, const float* __restrict__ gb_ih,
    const float* __restrict__ gb_hh,
    const float* __restrict__ kw1, const float* __restrict__ kb1,
    const float* __restrict__ kw2, const float* __restrict__ kb2,
    float* __restrict__ ws, int B)
{
    const int b = threadIdx.x;
    if (b >= B) return;
    const float knob = knobs[b];
    float a0 = kb2[0], a1 = kb2[1];
#pragma unroll
    for (int j = 0; j < 16; ++j) {
        const float hj = tanh_fast(fmaf(knob, kw1[j], kb1[j]));
        a0 = fmaf(hj, kw2[j], a0);
        a1 = fmaf(hj, kw2[16 + j], a1);
    }
    const float p0 = sigm_fast(a0);
    const float p1 = sigm_fast(a1);
    const float gain = fast_exp2(1.44269504088896341f * fmaf(p0, 4.0f, -2.0f));
    const float bias = 0.1f * p1;

    const float LOG2E = 1.44269504088896341f;
    const float TWOLOG2E = 2.88539008177792681f;
    const float kr_u = -LOG2E * gw_ih[0];
    const float kr_c = -LOG2E * (gb_ih[0] + gb_hh[0]);
    const float kz_u = -LOG2E * gw_ih[1];
    const float kz_c = -LOG2E * (gb_ih[1] + gb_hh[1]);
    const float kn_u = TWOLOG2E * gw_ih[2];
    const float kn_ci = TWOLOG2E * gb_ih[2];

    float* w = ws + b * 6;
    w[0] = kr_u * gain; w[1] = fmaf(kr_u, bias, kr_c);
    w[2] = kz_u * gain; w[3] = fmaf(kz_u, bias, kz_c);
    w[4] = kn_u * gain; w[5] = fmaf(kn_u, bias, kn_ci);
}

// ---- kernel 2: fused recurrence, phase-split -----------------------------
__global__ __launch_bounds__(256) void preamp_fused(
    const float* __restrict__ x,
    const float* __restrict__ pre_c, const float* __restrict__ post_c,
    const float* __restrict__ gw_hh, const float* __restrict__ gb_hh,
    const float* __restrict__ gw_out, const float* __restrict__ gb_out,
    const float* __restrict__ ws,
    float* __restrict__ out, int L, int cshift)
{
    const int tid = blockIdx.x * 256 + threadIdx.x;
    const int b = tid >> cshift;               // batch (nchunks = 1<<cshift)
    const int c = tid & ((1 << cshift) - 1);   // chunk within batch

    // ---- per-batch folded GRU input constants ----
    const float* w = ws + b * 6;
    const float Kry = w[0], Krc = w[1];
    const float Kzy = w[2], Kzc = w[3];
    const float Kny = w[4], Knc = w[5];

    // ---- filter coefficients (uniform -> scalar) ----
    const float f0b0 = pre_c[0],  f0b1 = pre_c[1],  f0b2 = pre_c[2];
    const float f0a1 = -pre_c[3], f0a2 = -pre_c[4];
    const float f1b0 = pre_c[5],  f1b1 = pre_c[6],  f1b2 = pre_c[7];
    const float f1a1 = -pre_c[8], f1a2 = -pre_c[9];
    const float f2b0 = post_c[0], f2b1 = post_c[1], f2b2 = post_c[2];
    const float f2a1 = -post_c[3], f2a2 = -post_c[4];
    const float f3b0 = post_c[5], f3b1 = post_c[6], f3b2 = post_c[7];
    const float f3a1 = -post_c[8], f3a2 = -post_c[9];

    // ---- h-side GRU constants (batch-independent) ----
    const float LOG2E = 1.44269504088896341f;
    const float TWOLOG2E = 2.88539008177792681f;
    const float kr_h = -LOG2E * gw_hh[0];
    const float kz_h = -LOG2E * gw_hh[1];
    const float kn_h = TWOLOG2E * gw_hh[2];
    const float kn_c = TWOLOG2E * gb_hh[2];
    const float wo = gw_out[0], bo = gb_out[0];

    const long base = (long)b * (long)L;
    const float* xp = x + base;
    float* op = out + base;
    const int t0 = c * CHUNK;

    // Phase macros. Each reads its input from (io) and overwrites it with
    // the stage output -- window buffer is reused in place across phases.
#define PRE_STEP(io)                                                         \
    {                                                                        \
        const float xt = (io);                                               \
        float ff = fmaf(f0b1, ax1, f0b0 * xt);                               \
        ff = fmaf(f0b2, ax2, ff);                                            \
        ff = fmaf(f0a2, ay2, ff);                                            \
        const float y = fmaf(f0a1, ay1, ff);                                 \
        ax2 = ax1; ax1 = xt; ay2 = ay1; ay1 = y;                             \
        float ff1 = fmaf(f1b1, bx1, f1b0 * y);                               \
        ff1 = fmaf(f1b2, bx2, ff1);                                          \
        ff1 = fmaf(f1a2, by2, ff1);                                          \
        const float y2 = fmaf(f1a1, by1, ff1);                               \
        bx2 = bx1; bx1 = y; by2 = by1; by1 = y2;                             \
        (io) = y2;                                                           \
    }
#define GRU_STEP(io)                                                         \
    {                                                                        \
        const float y2 = (io);                                               \
        const float ur = fmaf(Kry, y2, Krc);                                 \
        const float uz = fmaf(Kzy, y2, Kzc);                                 \
        const float un = fmaf(Kny, y2, Knc);                                 \
        const float hn = fmaf(kn_h, h, kn_c);                                \
        const float r = fast_rcp(1.0f + fast_exp2(fmaf(kr_h, h, ur)));       \
        const float z = fast_rcp(1.0f + fast_exp2(fmaf(kz_h, h, uz)));       \
        const float n = fmaf(-2.0f,                                          \
            fast_rcp(1.0f + fast_exp2(fmaf(r, hn, un))), 1.0f);              \
        h = fmaf(z, h - n, n);                                               \
        (io) = fmaf(wo, h, bo);                                              \
    }
#define POST_STEP(io)                                                        \
    {                                                                        \
        const float v = (io);                                                \
        float ff2 = fmaf(f2b1, cx1, f2b0 * v);                               \
        ff2 = fmaf(f2b2, cx2, ff2);                                          \
        ff2 = fmaf(f2a2, cy2, ff2);                                          \
        const float q = fmaf(f2a1, cy1, ff2);                                \
        cx2 = cx1; cx1 = v; cy2 = cy1; cy1 = q;                              \
        float ff3 = fmaf(f3b1, dx1, f3b0 * q);                               \
        ff3 = fmaf(f3b2, dx2, ff3);                                          \
        ff3 = fmaf(f3a2, dy2, ff3);                                          \
        const float q2 = fmaf(f3a1, dy1, ff3);                               \
        dx2 = dx1; dx1 = q; dy2 = dy1; dy1 = q2;                             \
        (io) = q2;                                                           \
    }

    if (c != 0) {
        // ---- full window: 8 quads, all loads up front ----
        const float* wb = xp + (t0 - WARMUP);
        float4 qb[NWQ];
#pragma unroll
        for (int i = 0; i < NWQ; ++i)
            qb[i] = *reinterpret_cast<const float4*>(wb + 4 * i);
        // phase 1: pre-biquads (x -> y2), 2-fma loop carry, high ILP
        {
            float ax1 = 0.f, ax2 = 0.f, ay1 = 0.f, ay2 = 0.f;
            float bx1 = 0.f, bx2 = 0.f, by1 = 0.f, by2 = 0.f;
#pragma unroll
            for (int i = 0; i < NWQ; ++i) {
                PRE_STEP(qb[i].x); PRE_STEP(qb[i].y);
                PRE_STEP(qb[i].z); PRE_STEP(qb[i].w);
            }
        }
        // phase 2: GRU (y2 -> v), the serial core
        {
            float h = 0.f;
#pragma unroll
            for (int i = 0; i < NWQ; ++i) {
                GRU_STEP(qb[i].x); GRU_STEP(qb[i].y);
                GRU_STEP(qb[i].z); GRU_STEP(qb[i].w);
            }
        }
        // phase 3: post-biquads (v -> q2), 2-fma loop carry
        {
            float cx1 = 0.f, cx2 = 0.f, cy1 = 0.f, cy2 = 0.f;
            float dx1 = 0.f, dx2 = 0.f, dy1 = 0.f, dy2 = 0.f;
#pragma unroll
            for (int i = 0; i < NWQ; ++i) {
                POST_STEP(qb[i].x); POST_STEP(qb[i].y);
                POST_STEP(qb[i].z); POST_STEP(qb[i].w);
            }
        }
        // store chunk half only
#pragma unroll
        for (int i = 0; i < NCQ; ++i)
            *reinterpret_cast<float4*>(op + t0 + 4 * i) = qb[WARMUP / 4 + i];
    } else {
        // ---- c == 0: zero states at t=0 are EXACT; no warm-up ----
        float4 qb[NCQ];
#pragma unroll
        for (int i = 0; i < NCQ; ++i)
            qb[i] = *reinterpret_cast<const float4*>(xp + 4 * i);
        {
            float ax1 = 0.f, ax2 = 0.f, ay1 = 0.f, ay2 = 0.f;
            float bx1 = 0.f, bx2 = 0.f, by1 = 0.f, by2 = 0.f;
#pragma unroll
            for (int i = 0; i < NCQ; ++i) {
                PRE_STEP(qb[i].x); PRE_STEP(qb[i].y);
                PRE_STEP(qb[i].z); PRE_STEP(qb[i].w);
            }
        }
        {
            float h = 0.f;
#pragma unroll
            for (int i = 0; i < NCQ; ++i) {
                GRU_STEP(qb[i].x); GRU_STEP(qb[i].y);
                GRU_STEP(qb[i].z); GRU_STEP(qb[i].w);
            }
        }
        {
            float cx1 = 0.f, cx2 = 0.f, cy1 = 0.f, cy2 = 0.f;
            float dx1 = 0.f, dx2 = 0.f, dy1 = 0.f, dy2 = 0.f;
#pragma unroll
            for (int i = 0; i < NCQ; ++i) {
                POST_STEP(qb[i].x); POST_STEP(qb[i].y);
                POST_STEP(qb[i].z); POST_STEP(qb[i].w);
            }
        }
#pragma unroll
        for (int i = 0; i < NCQ; ++i)
            *reinterpret_cast<float4*>(op + 4 * i) = qb[i];
    }
#undef PRE_STEP
#undef GRU_STEP
#undef POST_STEP
}

extern "C" void kernel_launch(void* const* d_in, const int* in_sizes, int n_in,
                              void* d_out, int out_size, void* d_ws, size_t ws_size,
                              hipStream_t stream) {
    const float* x      = (const float*)d_in[0];
    const float* knobs  = (const float*)d_in[1];
    const float* pre_c  = (const float*)d_in[2];
    const float* post_c = (const float*)d_in[3];
    const float* gw_ih  = (const float*)d_in[4];
    const float* gw_hh  = (const float*)d_in[5];
    const float* gb_ih  = (const float*)d_in[6];
    const float* gb_hh  = (const float*)d_in[7];
    const float* gw_out = (const float*)d_in[8];
    const float* gb_out = (const float*)d_in[9];
    const float* kw1    = (const float*)d_in[10];
    const float* kb1    = (const float*)d_in[11];
    const float* kw2    = (const float*)d_in[12];
    const float* kb2    = (const float*)d_in[13];
    float* out = (float*)d_out;
    float* ws  = (float*)d_ws;

    const int B = in_sizes[1];                 // 64
    const int L = in_sizes[0] / B;             // 65536
    const int nchunks = L / CHUNK;             // 4096 (power of two)
    int cshift = 0; while ((1 << cshift) < nchunks) ++cshift;
    const int threads = B * nchunks;           // 262144

    knob_precompute<<<dim3(1), dim3(64), 0, stream>>>(
        knobs, gw_ih, gb_ih, gb_hh, kw1, kb1, kw2, kb2, ws, B);
    preamp_fused<<<dim3(threads / 256), dim3(256), 0, stream>>>(
        x, pre_c, post_c, gw_hh, gb_hh, gw_out, gb_out, ws, out, L, cshift);
}